// Round 1
// baseline (708.037 us; speedup 1.0000x reference)
//
#include <hip/hip_runtime.h>

typedef unsigned short u16;

#define NTOK 8192
#define HD   1024
#define NEXP 8
#define CAP  2560   // ceil(1.25 * 8192 * 2 / 8) == 2560 == 20 * 128 tiles exactly

typedef __bf16 bf16x8 __attribute__((ext_vector_type(8)));
typedef float  f32x4  __attribute__((ext_vector_type(4)));

__device__ __forceinline__ u16 f2bf(float f){
  union { float f; unsigned u; } v; v.f = f;
  return (u16)((v.u + 0x7fffu + ((v.u >> 16) & 1u)) >> 16);   // RNE
}
__device__ __forceinline__ float bf2f(u16 h){
  union { unsigned u; float f; } v; v.u = ((unsigned)h) << 16; return v.f;
}

__device__ __forceinline__ void async16(const void* g, void* l){
  __builtin_amdgcn_global_load_lds((__attribute__((address_space(1))) void*)(g),
                                   (__attribute__((address_space(3))) void*)(l), 16, 0, 0);
}

// ---------------- fp32 -> bf16 cast ----------------
__global__ __launch_bounds__(256) void cast_kernel(const float* __restrict__ src,
                                                   u16* __restrict__ dst, int n4){
  int i = blockIdx.x * 256 + threadIdx.x;
  if (i >= n4) return;
  float4 v = ((const float4*)src)[i];
  ushort4 o;
  o.x = f2bf(v.x); o.y = f2bf(v.y); o.z = f2bf(v.z); o.w = f2bf(v.w);
  ((ushort4*)dst)[i] = o;
}

// ---------------- router: logits (fp64 acc), softmax, top-2, normalized weights ----------------
__global__ __launch_bounds__(256) void router_kernel(const float* __restrict__ x,
                                                     const float* __restrict__ gate_w,
                                                     int* __restrict__ topk_idx,
                                                     float* __restrict__ topk_w){
  __shared__ float gw[NEXP * HD];
  int t = threadIdx.x;
  for (int i = t; i < NEXP * HD; i += 256) gw[i] = gate_w[i];
  __syncthreads();
  int wave = t >> 6, l = t & 63;
  int tok = blockIdx.x * 4 + wave;
  const float* xr = x + (size_t)tok * HD;
  double acc[NEXP];
#pragma unroll
  for (int e = 0; e < NEXP; e++) acc[e] = 0.0;
  for (int j = 0; j < 16; j++){
    int h = j * 64 + l;
    double xv = (double)xr[h];
#pragma unroll
    for (int e = 0; e < NEXP; e++) acc[e] += xv * (double)gw[e * HD + h];
  }
#pragma unroll
  for (int e = 0; e < NEXP; e++){
    double v = acc[e];
#pragma unroll
    for (int off = 32; off > 0; off >>= 1) v += __shfl_down(v, off, 64);
    acc[e] = v;
  }
  if (l == 0){
    int i0 = 0; double l0 = acc[0];
#pragma unroll
    for (int e = 1; e < NEXP; e++) if (acc[e] > l0){ l0 = acc[e]; i0 = e; }
    int i1 = -1; double l1 = -1e300;
#pragma unroll
    for (int e = 0; e < NEXP; e++) if (e != i0 && acc[e] > l1){ l1 = acc[e]; i1 = e; }
    // normalized top-2 weights: softmax denominator cancels; 1e-20 negligible
    double e1 = exp(l1 - l0);
    double s  = 1.0 + e1;
    topk_idx[tok * 2 + 0] = i0;
    topk_idx[tok * 2 + 1] = i1;
    topk_w [tok * 2 + 0] = (float)(1.0 / s);
    topk_w [tok * 2 + 1] = (float)(e1 / s);
  }
}

// ---------------- capacity scan: stable per-expert slot positions ----------------
__global__ __launch_bounds__(256) void scan_kernel(const int* __restrict__ topk_idx,
                                                   const float* __restrict__ topk_w,
                                                   int* __restrict__ tok_list,
                                                   float* __restrict__ w_list,
                                                   int* __restrict__ ne){
  __shared__ int hist[256][NEXP];
  int t = threadIdx.x;
  const int SPT = (NTOK * 2) / 256;   // 64 slots per thread, contiguous => stable order
  int cnt[NEXP];
#pragma unroll
  for (int e = 0; e < NEXP; e++) cnt[e] = 0;
  int base = t * SPT;
  for (int s = 0; s < SPT; s++) cnt[topk_idx[base + s]]++;
#pragma unroll
  for (int e = 0; e < NEXP; e++) hist[t][e] = cnt[e];
  __syncthreads();
  if (t < NEXP){
    int run = 0;
    for (int i = 0; i < 256; i++){ int v = hist[i][t]; hist[i][t] = run; run += v; }
    ne[t] = run < CAP ? run : CAP;
  }
  __syncthreads();
  int pos[NEXP];
#pragma unroll
  for (int e = 0; e < NEXP; e++) pos[e] = hist[t][e];
  for (int s = 0; s < SPT; s++){
    int slot = base + s;
    int e = topk_idx[slot];
    int p = pos[e]++;
    if (p < CAP){                       // capacity drop
      tok_list[e * CAP + p] = slot >> 1;
      w_list [e * CAP + p] = topk_w[slot];
    }
  }
}

// ---------------- bf16 GEMM  C[M,N] = A[M,K] @ B[N,K]^T  (m97 structure) ----------------
// MODE: 0 = store bf16, 1 = silu(G)*acc -> bf16, 2 = store fp32, 3 = atomicAdd(w * acc) scatter
// IND : 1 = A rows indirected through tok_list (gather fused into staging)
#define MODE_BF16 0
#define MODE_SILU 1
#define MODE_F32  2
#define MODE_ATOM 3

template<int MODE, int IND>
__global__ __launch_bounds__(256)
void gemm_bt(const u16* __restrict__ A, long long sAe,
             const u16* __restrict__ B, long long sBe,
             void* __restrict__ Cv,     long long sCe,
             const u16* __restrict__ G, long long sGe,
             const int* __restrict__ tok_list, const float* __restrict__ w_list,
             const int* __restrict__ ne,
             int M, int N, int K, int ldc)
{
  __shared__ u16 As[128 * 64];
  __shared__ u16 Bs[128 * 64];

  const int e  = blockIdx.z;
  const int m0 = blockIdx.y * 128;
  const int n0 = blockIdx.x * 128;

  int n_valid = M;
  if (IND || MODE == MODE_ATOM) n_valid = ne[e];
  if (m0 >= n_valid) return;                       // whole tile past expert count

  const u16* Ae = A + (size_t)e * sAe;
  const u16* Be = B + (size_t)e * sBe;
  const int* tl = tok_list + e * CAP;

  const int tid = threadIdx.x;
  const int wv  = tid >> 6;
  const int l   = tid & 63;

  // staging source pointers: chunk = i*4+wv covers 8 rows; lane l -> row l>>3, col (l&7)*8
  const u16* aptr[4];
  const u16* bptr[4];
#pragma unroll
  for (int i = 0; i < 4; i++){
    int chunk = i * 4 + wv;
    int arow  = m0 + chunk * 8 + (l >> 3);
    if (IND){
      int r2 = arow < n_valid ? arow : (n_valid - 1);
      aptr[i] = Ae + (size_t)tl[r2] * K + ((l & 7) * 8);
    } else {
      aptr[i] = Ae + (size_t)arow * K + ((l & 7) * 8);
    }
    int brow = n0 + chunk * 8 + (l >> 3);
    bptr[i]  = Be + (size_t)brow * K + ((l & 7) * 8);
  }

  const int wm = wv & 1, wn = wv >> 1;
  const int col = l & 15, quad = l >> 4;

  f32x4 acc[4][4];
#pragma unroll
  for (int i = 0; i < 4; i++)
#pragma unroll
    for (int j = 0; j < 4; j++)
      acc[i][j] = (f32x4){0.f, 0.f, 0.f, 0.f};

  const int a_base = (wm * 64 + col) * 64 + quad * 8;
  const int b_base = (wn * 64 + col) * 64 + quad * 8;

  for (int k0 = 0; k0 < K; k0 += 64){
#pragma unroll
    for (int i = 0; i < 4; i++){
      int chunk = i * 4 + wv;
      async16(aptr[i] + k0, &As[chunk * 512 + l * 8]);
      async16(bptr[i] + k0, &Bs[chunk * 512 + l * 8]);
    }
    __syncthreads();     // drains vmcnt before barrier
#pragma unroll
    for (int ks = 0; ks < 64; ks += 32){
      bf16x8 a[4], b[4];
#pragma unroll
      for (int i = 0; i < 4; i++) a[i] = *(const bf16x8*)&As[a_base + i * (16 * 64) + ks];
#pragma unroll
      for (int j = 0; j < 4; j++) b[j] = *(const bf16x8*)&Bs[b_base + j * (16 * 64) + ks];
#pragma unroll
      for (int i = 0; i < 4; i++)
#pragma unroll
        for (int j = 0; j < 4; j++)
          acc[i][j] = __builtin_amdgcn_mfma_f32_16x16x32_bf16(a[i], b[j], acc[i][j], 0, 0, 0);
    }
    __syncthreads();
  }

  // epilogue: C/D layout col = lane&15, row = quad*4 + reg
  if (MODE == MODE_ATOM){
    float* C = (float*)Cv;
    const float* wl = w_list + e * CAP;
#pragma unroll
    for (int i = 0; i < 4; i++){
#pragma unroll
      for (int r = 0; r < 4; r++){
        int row = m0 + wm * 64 + i * 16 + quad * 4 + r;
        if (row < n_valid){
          int   tok = tl[row];
          float wgt = wl[row];
#pragma unroll
          for (int j = 0; j < 4; j++){
            int cg = n0 + wn * 64 + j * 16 + col;
            atomicAdd(&C[(size_t)tok * ldc + cg], wgt * acc[i][j][r]);
          }
        }
      }
    }
  } else if (MODE == MODE_F32){
    float* C = (float*)Cv;
#pragma unroll
    for (int i = 0; i < 4; i++)
#pragma unroll
      for (int r = 0; r < 4; r++){
        int row = m0 + wm * 64 + i * 16 + quad * 4 + r;
#pragma unroll
        for (int j = 0; j < 4; j++){
          int cg = n0 + wn * 64 + j * 16 + col;
          C[(size_t)row * ldc + cg] = acc[i][j][r];
        }
      }
  } else if (MODE == MODE_BF16){
    u16* C = (u16*)Cv + (size_t)e * sCe;
#pragma unroll
    for (int i = 0; i < 4; i++)
#pragma unroll
      for (int r = 0; r < 4; r++){
        int row = m0 + wm * 64 + i * 16 + quad * 4 + r;
#pragma unroll
        for (int j = 0; j < 4; j++){
          int cg = n0 + wn * 64 + j * 16 + col;
          C[(size_t)row * ldc + cg] = f2bf(acc[i][j][r]);
        }
      }
  } else { // MODE_SILU: h = silu(G) * acc, store bf16
    u16* C = (u16*)Cv + (size_t)e * sCe;
    const u16* Ge = G + (size_t)e * sGe;
#pragma unroll
    for (int i = 0; i < 4; i++)
#pragma unroll
      for (int r = 0; r < 4; r++){
        int row = m0 + wm * 64 + i * 16 + quad * 4 + r;
#pragma unroll
        for (int j = 0; j < 4; j++){
          int cg = n0 + wn * 64 + j * 16 + col;
          float g = bf2f(Ge[(size_t)row * ldc + cg]);
          float s = g / (1.f + __expf(-g));
          C[(size_t)row * ldc + cg] = f2bf(s * acc[i][j][r]);
        }
      }
  }
}

extern "C" void kernel_launch(void* const* d_in, const int* in_sizes, int n_in,
                              void* d_out, int out_size, void* d_ws, size_t ws_size,
                              hipStream_t stream){
  const float* x       = (const float*)d_in[0];
  const float* gate_w  = (const float*)d_in[1];
  const float* we_gate = (const float*)d_in[2];
  const float* we_up   = (const float*)d_in[3];
  const float* we_down = (const float*)d_in[4];
  const float* ws_gate = (const float*)d_in[5];
  const float* ws_up   = (const float*)d_in[6];
  const float* ws_down = (const float*)d_in[7];
  float* out = (float*)d_out;

  char* p = (char*)d_ws;
  u16* x_bf   = (u16*)p; p += (size_t)NTOK * HD * 2;
  u16* wg_bf  = (u16*)p; p += (size_t)NEXP * 1024 * 1024 * 2;
  u16* wu_bf  = (u16*)p; p += (size_t)NEXP * 1024 * 1024 * 2;
  u16* wd_bf  = (u16*)p; p += (size_t)NEXP * 1024 * 1024 * 2;
  u16* wsg_bf = (u16*)p; p += (size_t)2048 * 1024 * 2;
  u16* wsu_bf = (u16*)p; p += (size_t)2048 * 1024 * 2;
  u16* wsd_bf = (u16*)p; p += (size_t)1024 * 2048 * 2;
  u16* Gbuf   = (u16*)p; p += (size_t)NEXP * CAP * 1024 * 2;  // shared phase: [8192,2048] fits
  u16* Hbuf   = (u16*)p; p += (size_t)NEXP * CAP * 1024 * 2;
  int*   topk_idx = (int*)p;   p += (size_t)NTOK * 2 * 4;
  float* topk_w   = (float*)p; p += (size_t)NTOK * 2 * 4;
  int*   tok_list = (int*)p;   p += (size_t)NEXP * CAP * 4;
  float* w_list   = (float*)p; p += (size_t)NEXP * CAP * 4;
  int*   ne       = (int*)p;   p += 128;

  auto cast = [&](const float* s, u16* d, size_t n){
    int n4 = (int)(n / 4);
    cast_kernel<<<dim3((n4 + 255) / 256), dim3(256), 0, stream>>>(s, d, n4);
  };
  cast(x,       x_bf,   (size_t)NTOK * HD);
  cast(we_gate, wg_bf,  (size_t)NEXP * 1024 * 1024);
  cast(we_up,   wu_bf,  (size_t)NEXP * 1024 * 1024);
  cast(we_down, wd_bf,  (size_t)NEXP * 1024 * 1024);
  cast(ws_gate, wsg_bf, (size_t)2048 * 1024);
  cast(ws_up,   wsu_bf, (size_t)2048 * 1024);
  cast(ws_down, wsd_bf, (size_t)1024 * 2048);

  router_kernel<<<dim3(NTOK / 4), dim3(256), 0, stream>>>(x, gate_w, topk_idx, topk_w);
  scan_kernel<<<dim3(1), dim3(256), 0, stream>>>(topk_idx, topk_w, tok_list, w_list, ne);

  const long long WEXP = 1024LL * 1024;     // per-expert weight stride
  const long long SLOT = (long long)CAP * 1024;

  // ---- shared expert: G = x@wsg^T ; H = silu(G)*(x@wsu^T) ; out = H@wsd^T ----
  gemm_bt<MODE_BF16, 0><<<dim3(16, 64, 1), 256, 0, stream>>>(
      x_bf, 0, wsg_bf, 0, Gbuf, 0, nullptr, 0, tok_list, w_list, ne, 8192, 2048, 1024, 2048);
  gemm_bt<MODE_SILU, 0><<<dim3(16, 64, 1), 256, 0, stream>>>(
      x_bf, 0, wsu_bf, 0, Hbuf, 0, Gbuf, 0, tok_list, w_list, ne, 8192, 2048, 1024, 2048);
  gemm_bt<MODE_F32, 0><<<dim3(8, 64, 1), 256, 0, stream>>>(
      Hbuf, 0, wsd_bf, 0, out, 0, nullptr, 0, tok_list, w_list, ne, 8192, 1024, 2048, 1024);

  // ---- routed experts (grouped, token-gather fused into A staging) ----
  gemm_bt<MODE_BF16, 1><<<dim3(8, 20, 8), 256, 0, stream>>>(
      x_bf, 0, wg_bf, WEXP, Gbuf, SLOT, nullptr, 0, tok_list, w_list, ne, CAP, 1024, 1024, 1024);
  gemm_bt<MODE_SILU, 1><<<dim3(8, 20, 8), 256, 0, stream>>>(
      x_bf, 0, wu_bf, WEXP, Hbuf, SLOT, Gbuf, SLOT, tok_list, w_list, ne, CAP, 1024, 1024, 1024);
  gemm_bt<MODE_ATOM, 0><<<dim3(8, 20, 8), 256, 0, stream>>>(
      Hbuf, SLOT, wd_bf, WEXP, out, 0, nullptr, 0, tok_list, w_list, ne, CAP, 1024, 1024, 1024);
}

// Round 2
// 588.967 us; speedup vs baseline: 1.2022x; 1.2022x over previous
//
#include <hip/hip_runtime.h>

typedef unsigned short u16;

#define NTOK 8192
#define HD   1024
#define NEXP 8
#define CAP  2560   // ceil(1.25 * 8192 * 2 / 8) == 2560 == 20 * 128 tiles exactly

typedef __bf16 bf16x8 __attribute__((ext_vector_type(8)));
typedef float  f32x4  __attribute__((ext_vector_type(4)));

__device__ __forceinline__ u16 f2bf(float f){
  union { float f; unsigned u; } v; v.f = f;
  return (u16)((v.u + 0x7fffu + ((v.u >> 16) & 1u)) >> 16);   // RNE
}
__device__ __forceinline__ float bf2f(u16 h){
  union { unsigned u; float f; } v; v.u = ((unsigned)h) << 16; return v.f;
}

__device__ __forceinline__ void async16(const void* g, void* l){
  __builtin_amdgcn_global_load_lds((__attribute__((address_space(1))) void*)(g),
                                   (__attribute__((address_space(3))) void*)(l), 16, 0, 0);
}

// ---------------- fp32 -> bf16 cast ----------------
__global__ __launch_bounds__(256) void cast_kernel(const float* __restrict__ src,
                                                   u16* __restrict__ dst, int n4){
  int i = blockIdx.x * 256 + threadIdx.x;
  if (i >= n4) return;
  float4 v = ((const float4*)src)[i];
  ushort4 o;
  o.x = f2bf(v.x); o.y = f2bf(v.y); o.z = f2bf(v.z); o.w = f2bf(v.w);
  ((ushort4*)dst)[i] = o;
}

// ---------------- router: logits (fp64 acc), softmax, top-2, normalized weights ----------------
__global__ __launch_bounds__(256) void router_kernel(const float* __restrict__ x,
                                                     const float* __restrict__ gate_w,
                                                     int* __restrict__ topk_idx,
                                                     float* __restrict__ topk_w){
  __shared__ float gw[NEXP * HD];
  int t = threadIdx.x;
  for (int i = t; i < NEXP * HD; i += 256) gw[i] = gate_w[i];
  __syncthreads();
  int wave = t >> 6, l = t & 63;
  int tok = blockIdx.x * 4 + wave;
  const float* xr = x + (size_t)tok * HD;
  double acc[NEXP];
#pragma unroll
  for (int e = 0; e < NEXP; e++) acc[e] = 0.0;
  for (int j = 0; j < 16; j++){
    int h = j * 64 + l;
    double xv = (double)xr[h];
#pragma unroll
    for (int e = 0; e < NEXP; e++) acc[e] += xv * (double)gw[e * HD + h];
  }
#pragma unroll
  for (int e = 0; e < NEXP; e++){
    double v = acc[e];
#pragma unroll
    for (int off = 32; off > 0; off >>= 1) v += __shfl_down(v, off, 64);
    acc[e] = v;
  }
  if (l == 0){
    int i0 = 0; double l0 = acc[0];
#pragma unroll
    for (int e = 1; e < NEXP; e++) if (acc[e] > l0){ l0 = acc[e]; i0 = e; }
    int i1 = -1; double l1 = -1e300;
#pragma unroll
    for (int e = 0; e < NEXP; e++) if (e != i0 && acc[e] > l1){ l1 = acc[e]; i1 = e; }
    double e1 = exp(l1 - l0);
    double s  = 1.0 + e1;
    topk_idx[tok * 2 + 0] = i0;
    topk_idx[tok * 2 + 1] = i1;
    topk_w [tok * 2 + 0] = (float)(1.0 / s);
    topk_w [tok * 2 + 1] = (float)(e1 / s);
  }
}

// ---------------- capacity scan: stable per-expert slot positions + token->slot map ----------------
__global__ __launch_bounds__(256) void scan_kernel(const int* __restrict__ topk_idx,
                                                   const float* __restrict__ topk_w,
                                                   int* __restrict__ tok_list,
                                                   float* __restrict__ w_list,
                                                   int* __restrict__ slot_map,
                                                   int* __restrict__ ne){
  __shared__ int hist[256][NEXP];
  int t = threadIdx.x;
  const int SPT = (NTOK * 2) / 256;   // 64 slots per thread, contiguous => stable order
  int cnt[NEXP];
#pragma unroll
  for (int e = 0; e < NEXP; e++) cnt[e] = 0;
  int base = t * SPT;
  for (int s = 0; s < SPT; s++) cnt[topk_idx[base + s]]++;
#pragma unroll
  for (int e = 0; e < NEXP; e++) hist[t][e] = cnt[e];
  __syncthreads();
  if (t < NEXP){
    int run = 0;
    for (int i = 0; i < 256; i++){ int v = hist[i][t]; hist[i][t] = run; run += v; }
    ne[t] = run < CAP ? run : CAP;
  }
  __syncthreads();
  int pos[NEXP];
#pragma unroll
  for (int e = 0; e < NEXP; e++) pos[e] = hist[t][e];
  for (int s = 0; s < SPT; s++){
    int slot = base + s;
    int e = topk_idx[slot];
    int p = pos[e]++;
    if (p < CAP){
      tok_list[e * CAP + p] = slot >> 1;
      w_list [e * CAP + p] = topk_w[slot];
      slot_map[slot] = e * CAP + p;
    } else {
      slot_map[slot] = -1;                // capacity-dropped
    }
  }
}

// ---------------- bf16 GEMM  C[M,N] = A[M,K] @ B[N,K]^T  (m97 structure + XOR bank swizzle) ----------------
// MODE_GU   : B-tile = 64 gate rows + 64 up rows; epilogue silu(g)*u -> bf16 (N-tile covers 64 I-cols)
// MODE_WBF  : C = w_list[row] * acc -> bf16 (per-slot routed down output)
// MODE_FINAL: C = acc + Ebuf[slot0] + Ebuf[slot1] -> fp32 (shared down + routed combine)
// IND       : A rows gathered through tok_list (fused into staging)
#define MODE_GU    0
#define MODE_WBF   1
#define MODE_FINAL 2

template<int MODE, int IND>
__global__ __launch_bounds__(256)
void gemm_bt(const u16* __restrict__ A, long long sAe,
             const u16* __restrict__ B0, const u16* __restrict__ B1, long long sBe,
             void* __restrict__ Cv, long long sCe, int ldc,
             const int* __restrict__ tok_list, const float* __restrict__ w_list,
             const int* __restrict__ ne,
             const u16* __restrict__ Ebuf, const int* __restrict__ slot_map,
             int M, int K)
{
  __shared__ u16 As[128 * 64];
  __shared__ u16 Bs[128 * 64];

  const int e  = blockIdx.z;
  const int m0 = blockIdx.y * 128;
  const int n0 = blockIdx.x * ((MODE == MODE_GU) ? 64 : 128);

  int n_valid = (IND || MODE == MODE_WBF) ? ne[e] : M;
  if (m0 >= n_valid) return;

  const u16* Ae = A + (size_t)e * sAe;
  const int* tl = tok_list + e * CAP;

  const int tid = threadIdx.x;
  const int wv  = tid >> 6;
  const int l   = tid & 63;
  const int lr  = l >> 3;             // row within 8-row chunk
  const int cb  = (l & 7) ^ lr;       // XOR-swizzled col-block (16B units)

  // staging source pointers; chunk = i*4+wv covers 8 tile-rows
  const u16* aptr[4];
  const u16* bptr[4];
#pragma unroll
  for (int i = 0; i < 4; i++){
    int chunk = i * 4 + wv;
    int arow  = m0 + chunk * 8 + lr;
    if (IND){
      int r2 = arow < n_valid ? arow : (n_valid - 1);
      aptr[i] = Ae + (size_t)tl[r2] * K + cb * 8;
    } else {
      aptr[i] = Ae + (size_t)arow * K + cb * 8;
    }
    int rn = chunk * 8 + lr;          // B tile row 0..127
    if (MODE == MODE_GU){
      int w  = rn >> 6;               // which wave-half of N
      int jq = (rn >> 4) & 3;         // 0,1 = gate ; 2,3 = up  (uniform per chunk)
      int rl = rn & 15;
      int icol = n0 + w * 32 + (jq & 1) * 16 + rl;
      const u16* src = (jq < 2) ? B0 : B1;
      bptr[i] = src + (size_t)e * sBe + (size_t)icol * K + cb * 8;
    } else {
      bptr[i] = B0 + (size_t)e * sBe + (size_t)(n0 + rn) * K + cb * 8;
    }
  }

  const int wm = wv & 1, wn = wv >> 1;
  const int col = l & 15, quad = l >> 4;
  const int rr = col & 7, ch = col >> 3;

  f32x4 acc[4][4];
#pragma unroll
  for (int i = 0; i < 4; i++)
#pragma unroll
    for (int j = 0; j < 4; j++)
      acc[i][j] = (f32x4){0.f, 0.f, 0.f, 0.f};

  for (int k0 = 0; k0 < K; k0 += 64){
#pragma unroll
    for (int i = 0; i < 4; i++){
      int chunk = i * 4 + wv;
      async16(aptr[i] + k0, &As[chunk * 512 + l * 8]);
      async16(bptr[i] + k0, &Bs[chunk * 512 + l * 8]);
    }
    __syncthreads();
#pragma unroll
    for (int s = 0; s < 2; s++){
      const int so = (rr * 8 + ((quad + s * 4) ^ rr)) * 8;   // swizzled fragment offset
      bf16x8 a[4], b[4];
#pragma unroll
      for (int i = 0; i < 4; i++) a[i] = *(const bf16x8*)&As[(wm * 8 + i * 2 + ch) * 512 + so];
#pragma unroll
      for (int j = 0; j < 4; j++) b[j] = *(const bf16x8*)&Bs[(wn * 8 + j * 2 + ch) * 512 + so];
#pragma unroll
      for (int i = 0; i < 4; i++)
#pragma unroll
        for (int j = 0; j < 4; j++)
          acc[i][j] = __builtin_amdgcn_mfma_f32_16x16x32_bf16(a[i], b[j], acc[i][j], 0, 0, 0);
    }
    __syncthreads();
  }

  // epilogue: C/D layout col = lane&15, row = quad*4 + reg
  if (MODE == MODE_GU){
    u16* C = (u16*)Cv + (size_t)e * sCe;
#pragma unroll
    for (int i = 0; i < 4; i++)
#pragma unroll
      for (int r = 0; r < 4; r++){
        int row = m0 + wm * 64 + i * 16 + quad * 4 + r;
#pragma unroll
        for (int j = 0; j < 2; j++){
          int cg = n0 + wn * 32 + j * 16 + col;
          float g = acc[i][j][r], u = acc[i][j + 2][r];
          float h = (g / (1.f + __expf(-g))) * u;
          C[(size_t)row * ldc + cg] = f2bf(h);
        }
      }
  } else if (MODE == MODE_WBF){
    u16* C = (u16*)Cv + (size_t)e * sCe;
    const float* wl = w_list + e * CAP;
#pragma unroll
    for (int i = 0; i < 4; i++)
#pragma unroll
      for (int r = 0; r < 4; r++){
        int row = m0 + wm * 64 + i * 16 + quad * 4 + r;
        if (row < n_valid){
          float wgt = wl[row];
#pragma unroll
          for (int j = 0; j < 4; j++){
            int cg = n0 + wn * 64 + j * 16 + col;
            C[(size_t)row * ldc + cg] = f2bf(wgt * acc[i][j][r]);
          }
        }
      }
  } else { // MODE_FINAL
    float* C = (float*)Cv;
#pragma unroll
    for (int i = 0; i < 4; i++)
#pragma unroll
      for (int r = 0; r < 4; r++){
        int row = m0 + wm * 64 + i * 16 + quad * 4 + r;
        int s0 = slot_map[row * 2 + 0];
        int s1 = slot_map[row * 2 + 1];
#pragma unroll
        for (int j = 0; j < 4; j++){
          int cg = n0 + wn * 64 + j * 16 + col;
          float v = acc[i][j][r];
          if (s0 >= 0) v += bf2f(Ebuf[(size_t)s0 * HD + cg]);
          if (s1 >= 0) v += bf2f(Ebuf[(size_t)s1 * HD + cg]);
          C[(size_t)row * HD + cg] = v;
        }
      }
  }
}

extern "C" void kernel_launch(void* const* d_in, const int* in_sizes, int n_in,
                              void* d_out, int out_size, void* d_ws, size_t ws_size,
                              hipStream_t stream){
  const float* x       = (const float*)d_in[0];
  const float* gate_w  = (const float*)d_in[1];
  const float* we_gate = (const float*)d_in[2];
  const float* we_up   = (const float*)d_in[3];
  const float* we_down = (const float*)d_in[4];
  const float* ws_gate = (const float*)d_in[5];
  const float* ws_up   = (const float*)d_in[6];
  const float* ws_down = (const float*)d_in[7];
  float* out = (float*)d_out;

  char* p = (char*)d_ws;
  u16* x_bf   = (u16*)p; p += (size_t)NTOK * HD * 2;
  u16* wg_bf  = (u16*)p; p += (size_t)NEXP * 1024 * 1024 * 2;
  u16* wu_bf  = (u16*)p; p += (size_t)NEXP * 1024 * 1024 * 2;
  u16* wd_bf  = (u16*)p; p += (size_t)NEXP * 1024 * 1024 * 2;
  u16* wsg_bf = (u16*)p; p += (size_t)2048 * 1024 * 2;
  u16* wsu_bf = (u16*)p; p += (size_t)2048 * 1024 * 2;
  u16* wsd_bf = (u16*)p; p += (size_t)1024 * 2048 * 2;
  u16* Hbuf   = (u16*)p; p += (size_t)NEXP * CAP * 1024 * 2;  // routed H; later reused as shared H [8192x2048]
  u16* Ebuf   = (u16*)p; p += (size_t)NEXP * CAP * 1024 * 2;  // per-slot weighted down output (bf16)
  int*   topk_idx = (int*)p;   p += (size_t)NTOK * 2 * 4;
  float* topk_w   = (float*)p; p += (size_t)NTOK * 2 * 4;
  int*   tok_list = (int*)p;   p += (size_t)NEXP * CAP * 4;
  float* w_list   = (float*)p; p += (size_t)NEXP * CAP * 4;
  int*   slot_map = (int*)p;   p += (size_t)NTOK * 2 * 4;
  int*   ne       = (int*)p;   p += 128;

  auto cast = [&](const float* s, u16* d, size_t n){
    int n4 = (int)(n / 4);
    cast_kernel<<<dim3((n4 + 255) / 256), dim3(256), 0, stream>>>(s, d, n4);
  };
  cast(x,       x_bf,   (size_t)NTOK * HD);
  cast(we_gate, wg_bf,  (size_t)NEXP * 1024 * 1024);
  cast(we_up,   wu_bf,  (size_t)NEXP * 1024 * 1024);
  cast(we_down, wd_bf,  (size_t)NEXP * 1024 * 1024);
  cast(ws_gate, wsg_bf, (size_t)2048 * 1024);
  cast(ws_up,   wsu_bf, (size_t)2048 * 1024);
  cast(ws_down, wsd_bf, (size_t)1024 * 2048);

  router_kernel<<<dim3(NTOK / 4), dim3(256), 0, stream>>>(x, gate_w, topk_idx, topk_w);
  scan_kernel<<<dim3(1), dim3(256), 0, stream>>>(topk_idx, topk_w, tok_list, w_list, slot_map, ne);

  const long long WEXP = 1024LL * 1024;      // per-expert weight stride
  const long long SLOT = (long long)CAP * 1024;

  // ---- routed: fused gate+up SwiGLU -> Hbuf ; weighted down -> Ebuf ----
  gemm_bt<MODE_GU, 1><<<dim3(16, 20, 8), 256, 0, stream>>>(
      x_bf, 0, wg_bf, wu_bf, WEXP, Hbuf, SLOT, 1024,
      tok_list, w_list, ne, nullptr, nullptr, CAP, 1024);
  gemm_bt<MODE_WBF, 0><<<dim3(8, 20, 8), 256, 0, stream>>>(
      Hbuf, SLOT, wd_bf, nullptr, WEXP, Ebuf, SLOT, 1024,
      tok_list, w_list, ne, nullptr, nullptr, CAP, 1024);

  // ---- shared: fused gate+up SwiGLU -> Hbuf(reused) ; down + routed-combine -> out ----
  gemm_bt<MODE_GU, 0><<<dim3(32, 64, 1), 256, 0, stream>>>(
      x_bf, 0, wsg_bf, wsu_bf, 0, Hbuf, 0, 2048,
      tok_list, w_list, ne, nullptr, nullptr, 8192, 1024);
  gemm_bt<MODE_FINAL, 0><<<dim3(8, 64, 1), 256, 0, stream>>>(
      Hbuf, 0, wsd_bf, nullptr, 0, out, 0, 1024,
      tok_list, w_list, ne, Ebuf, slot_map, 8192, 2048);
}

// Round 3
// 555.663 us; speedup vs baseline: 1.2742x; 1.0599x over previous
//
#include <hip/hip_runtime.h>

typedef unsigned short u16;

#define NTOK 8192
#define HD   1024
#define NEXP 8
#define CAP  2560   // ceil(1.25 * 8192 * 2 / 8) == 2560 == 20 * 128 tiles exactly

typedef __bf16 bf16x8 __attribute__((ext_vector_type(8)));
typedef float  f32x4  __attribute__((ext_vector_type(4)));

__device__ __forceinline__ u16 f2bf(float f){
  union { float f; unsigned u; } v; v.f = f;
  return (u16)((v.u + 0x7fffu + ((v.u >> 16) & 1u)) >> 16);   // RNE
}
__device__ __forceinline__ float bf2f(u16 h){
  union { unsigned u; float f; } v; v.u = ((unsigned)h) << 16; return v.f;
}

__device__ __forceinline__ void async16(const void* g, void* l){
  __builtin_amdgcn_global_load_lds((__attribute__((address_space(1))) void*)(g),
                                   (__attribute__((address_space(3))) void*)(l), 16, 0, 0);
}

// ---------------- prep: all 7 fp32->bf16 casts + router fused in one launch ----------------
// blocks [0,2048): router (4 tokens/block, fp64 logits, top-2, normalized weights)
// blocks [2048,40960): segmented float4 cast of the 7 input tensors
__global__ __launch_bounds__(256)
void prep_kernel(const float* __restrict__ x, const float* __restrict__ gate_w,
                 const float* __restrict__ we_gate, const float* __restrict__ we_up,
                 const float* __restrict__ we_down, const float* __restrict__ ws_gate,
                 const float* __restrict__ ws_up, const float* __restrict__ ws_down,
                 u16* __restrict__ x_bf, u16* __restrict__ wg_bf, u16* __restrict__ wu_bf,
                 u16* __restrict__ wd_bf, u16* __restrict__ wsg_bf, u16* __restrict__ wsu_bf,
                 u16* __restrict__ wsd_bf,
                 int* __restrict__ topk_idx, float* __restrict__ topk_w){
  __shared__ float gw[NEXP * HD];
  int bid = blockIdx.x;
  int t = threadIdx.x;
  if (bid < 2048){
    // ---- router ----
    for (int i = t; i < NEXP * HD; i += 256) gw[i] = gate_w[i];
    __syncthreads();
    int wave = t >> 6, l = t & 63;
    int tok = bid * 4 + wave;
    const float* xr = x + (size_t)tok * HD;
    double acc[NEXP];
#pragma unroll
    for (int e = 0; e < NEXP; e++) acc[e] = 0.0;
    for (int j = 0; j < 16; j++){
      int h = j * 64 + l;
      double xv = (double)xr[h];
#pragma unroll
      for (int e = 0; e < NEXP; e++) acc[e] += xv * (double)gw[e * HD + h];
    }
#pragma unroll
    for (int e = 0; e < NEXP; e++){
      double v = acc[e];
#pragma unroll
      for (int off = 32; off > 0; off >>= 1) v += __shfl_down(v, off, 64);
      acc[e] = v;
    }
    if (l == 0){
      int i0 = 0; double l0 = acc[0];
#pragma unroll
      for (int e = 1; e < NEXP; e++) if (acc[e] > l0){ l0 = acc[e]; i0 = e; }
      int i1 = -1; double l1 = -1e300;
#pragma unroll
      for (int e = 0; e < NEXP; e++) if (e != i0 && acc[e] > l1){ l1 = acc[e]; i1 = e; }
      double e1 = exp(l1 - l0);
      double s  = 1.0 + e1;
      topk_idx[tok * 2 + 0] = i0;
      topk_idx[tok * 2 + 1] = i1;
      topk_w [tok * 2 + 0] = (float)(1.0 / s);
      topk_w [tok * 2 + 1] = (float)(e1 / s);
    }
  } else {
    // ---- cast (segments are multiples of 256 float4s; blocks never straddle) ----
    long long g = (long long)(bid - 2048) * 256 + t;   // float4 index
    const float4* s; ushort4* d; long long off;
    if      (g <  2097152){ s = (const float4*)x;       d = (ushort4*)x_bf;   off = 0; }
    else if (g <  4194304){ s = (const float4*)we_gate; d = (ushort4*)wg_bf;  off = 2097152; }
    else if (g <  6291456){ s = (const float4*)we_up;   d = (ushort4*)wu_bf;  off = 4194304; }
    else if (g <  8388608){ s = (const float4*)we_down; d = (ushort4*)wd_bf;  off = 6291456; }
    else if (g <  8912896){ s = (const float4*)ws_gate; d = (ushort4*)wsg_bf; off = 8388608; }
    else if (g <  9437184){ s = (const float4*)ws_up;   d = (ushort4*)wsu_bf; off = 8912896; }
    else                  { s = (const float4*)ws_down; d = (ushort4*)wsd_bf; off = 9437184; }
    long long i = g - off;
    float4 v = s[i];
    ushort4 o;
    o.x = f2bf(v.x); o.y = f2bf(v.y); o.z = f2bf(v.z); o.w = f2bf(v.w);
    d[i] = o;
  }
}

// ---------------- capacity scan: stable per-expert slot positions + token->slot map ----------------
__global__ __launch_bounds__(256) void scan_kernel(const int* __restrict__ topk_idx,
                                                   const float* __restrict__ topk_w,
                                                   int* __restrict__ tok_list,
                                                   float* __restrict__ w_list,
                                                   int* __restrict__ slot_map,
                                                   int* __restrict__ ne){
  __shared__ int hist[256][NEXP];
  int t = threadIdx.x;
  const int SPT = (NTOK * 2) / 256;   // 64 slots per thread, contiguous => stable order
  int cnt[NEXP];
#pragma unroll
  for (int e = 0; e < NEXP; e++) cnt[e] = 0;
  int base = t * SPT;
  for (int s = 0; s < SPT; s++) cnt[topk_idx[base + s]]++;
#pragma unroll
  for (int e = 0; e < NEXP; e++) hist[t][e] = cnt[e];
  __syncthreads();
  if (t < NEXP){
    int run = 0;
    for (int i = 0; i < 256; i++){ int v = hist[i][t]; hist[i][t] = run; run += v; }
    ne[t] = run < CAP ? run : CAP;
  }
  __syncthreads();
  int pos[NEXP];
#pragma unroll
  for (int e = 0; e < NEXP; e++) pos[e] = hist[t][e];
  for (int s = 0; s < SPT; s++){
    int slot = base + s;
    int e = topk_idx[slot];
    int p = pos[e]++;
    if (p < CAP){
      tok_list[e * CAP + p] = slot >> 1;
      w_list [e * CAP + p] = topk_w[slot];
      slot_map[slot] = e * CAP + p;
    } else {
      slot_map[slot] = -1;                // capacity-dropped
    }
  }
}

// ---------------- merged SwiGLU GEMM: routed (8 experts, gathered) + shared, one launch ----------------
// C[M,64-wide N-tile] per block; B-tile = 64 gate rows + 64 up rows; epilogue silu(g)*u -> bf16.
// blocks [0,2560): routed  e=bid/320, m=(bid%320)/16, n=bid%16  (A gathered via tok_list)
// blocks [2560,4608): shared b2: n=b2/64, m=b2%64 (m fastest -> B reuse within XCD)
__global__ __launch_bounds__(256)
void gu_kernel(const u16* __restrict__ x_bf,
               const u16* __restrict__ wg, const u16* __restrict__ wu,
               const u16* __restrict__ wsg, const u16* __restrict__ wsu,
               u16* __restrict__ Hr, u16* __restrict__ Hs,
               const int* __restrict__ tok_list, const int* __restrict__ ne)
{
  __shared__ u16 As[128 * 64];
  __shared__ u16 Bs[128 * 64];

  const int bid = blockIdx.x;
  const bool routed = bid < 2560;
  int m0, n0, ldc, n_valid;
  const u16 *B0, *B1;
  u16* C;
  const int* tl = nullptr;
  if (routed){
    int e = bid / 320, r = bid % 320;
    m0 = (r / 16) * 128; n0 = (r % 16) * 64;
    B0 = wg + (size_t)e * (1024 * 1024);
    B1 = wu + (size_t)e * (1024 * 1024);
    C  = Hr + (size_t)e * (CAP * 1024);
    ldc = 1024;
    n_valid = ne[e];
    tl = tok_list + e * CAP;
    if (m0 >= n_valid) return;
  } else {
    int b2 = bid - 2560;
    n0 = (b2 / 64) * 64; m0 = (b2 % 64) * 128;
    B0 = wsg; B1 = wsu; C = Hs; ldc = 2048; n_valid = 1 << 30;
  }

  const int tid = threadIdx.x;
  const int wv  = tid >> 6;
  const int l   = tid & 63;
  const int lr  = l >> 3;             // row within 8-row chunk
  const int cb  = (l & 7) ^ lr;       // XOR-swizzled col-block (16B units)

  const u16* aptr[4];
  const u16* bptr[4];
#pragma unroll
  for (int i = 0; i < 4; i++){
    int chunk = i * 4 + wv;
    int arow  = m0 + chunk * 8 + lr;
    if (routed){
      int r2 = arow < n_valid ? arow : (n_valid - 1);
      aptr[i] = x_bf + (size_t)tl[r2] * 1024 + cb * 8;
    } else {
      aptr[i] = x_bf + (size_t)arow * 1024 + cb * 8;
    }
    int rn = chunk * 8 + lr;          // B tile row 0..127
    int w  = rn >> 6;                 // which wave-half of N
    int jq = (rn >> 4) & 3;           // 0,1 = gate ; 2,3 = up (uniform per chunk)
    int rl = rn & 15;
    int icol = n0 + w * 32 + (jq & 1) * 16 + rl;
    bptr[i] = ((jq < 2) ? B0 : B1) + (size_t)icol * 1024 + cb * 8;
  }

  const int wm = wv & 1, wn = wv >> 1;
  const int col = l & 15, quad = l >> 4;
  const int rr = col & 7, ch = col >> 3;

  f32x4 acc[4][4];
#pragma unroll
  for (int i = 0; i < 4; i++)
#pragma unroll
    for (int j = 0; j < 4; j++)
      acc[i][j] = (f32x4){0.f, 0.f, 0.f, 0.f};

  for (int k0 = 0; k0 < 1024; k0 += 64){
#pragma unroll
    for (int i = 0; i < 4; i++){
      int chunk = i * 4 + wv;
      async16(aptr[i] + k0, &As[chunk * 512 + l * 8]);
      async16(bptr[i] + k0, &Bs[chunk * 512 + l * 8]);
    }
    __syncthreads();
#pragma unroll
    for (int s = 0; s < 2; s++){
      const int so = (rr * 8 + ((quad + s * 4) ^ rr)) * 8;   // swizzled fragment offset
      bf16x8 a[4], b[4];
#pragma unroll
      for (int i = 0; i < 4; i++) a[i] = *(const bf16x8*)&As[(wm * 8 + i * 2 + ch) * 512 + so];
#pragma unroll
      for (int j = 0; j < 4; j++) b[j] = *(const bf16x8*)&Bs[(wn * 8 + j * 2 + ch) * 512 + so];
#pragma unroll
      for (int i = 0; i < 4; i++)
#pragma unroll
        for (int j = 0; j < 4; j++)
          acc[i][j] = __builtin_amdgcn_mfma_f32_16x16x32_bf16(a[i], b[j], acc[i][j], 0, 0, 0);
    }
    __syncthreads();
  }

  // epilogue: C/D layout col = lane&15, row = quad*4 + reg; silu(g)*u
#pragma unroll
  for (int i = 0; i < 4; i++)
#pragma unroll
    for (int r = 0; r < 4; r++){
      int row = m0 + wm * 64 + i * 16 + quad * 4 + r;
#pragma unroll
      for (int j = 0; j < 2; j++){
        int cg = n0 + wn * 32 + j * 16 + col;
        float g = acc[i][j][r], u = acc[i][j + 2][r];
        float h = (g / (1.f + __expf(-g))) * u;
        C[(size_t)row * ldc + cg] = f2bf(h);
      }
    }
}

// ---------------- bf16 GEMM  C[M,N] = A[M,K] @ B[N,K]^T  (m97 structure + XOR bank swizzle) ----------------
// MODE_WBF  : C = w_list[row] * acc -> bf16 (per-slot routed down output)
// MODE_FINAL: C = acc + Ebuf[slot0] + Ebuf[slot1] -> fp32 (shared down + routed combine)
#define MODE_WBF   1
#define MODE_FINAL 2

template<int MODE>
__global__ __launch_bounds__(256)
void gemm_bt(const u16* __restrict__ A, long long sAe,
             const u16* __restrict__ B0, long long sBe,
             void* __restrict__ Cv, long long sCe, int ldc,
             const float* __restrict__ w_list, const int* __restrict__ ne,
             const u16* __restrict__ Ebuf, const int* __restrict__ slot_map,
             int M, int K)
{
  __shared__ u16 As[128 * 64];
  __shared__ u16 Bs[128 * 64];

  const int e  = blockIdx.z;
  const int m0 = blockIdx.y * 128;
  const int n0 = blockIdx.x * 128;

  int n_valid = (MODE == MODE_WBF) ? ne[e] : M;
  if (m0 >= n_valid) return;

  const u16* Ae = A + (size_t)e * sAe;

  const int tid = threadIdx.x;
  const int wv  = tid >> 6;
  const int l   = tid & 63;
  const int lr  = l >> 3;
  const int cb  = (l & 7) ^ lr;

  const u16* aptr[4];
  const u16* bptr[4];
#pragma unroll
  for (int i = 0; i < 4; i++){
    int chunk = i * 4 + wv;
    int arow  = m0 + chunk * 8 + lr;
    aptr[i] = Ae + (size_t)arow * K + cb * 8;
    int brow = n0 + chunk * 8 + lr;
    bptr[i] = B0 + (size_t)e * sBe + (size_t)brow * K + cb * 8;
  }

  const int wm = wv & 1, wn = wv >> 1;
  const int col = l & 15, quad = l >> 4;
  const int rr = col & 7, ch = col >> 3;

  f32x4 acc[4][4];
#pragma unroll
  for (int i = 0; i < 4; i++)
#pragma unroll
    for (int j = 0; j < 4; j++)
      acc[i][j] = (f32x4){0.f, 0.f, 0.f, 0.f};

  for (int k0 = 0; k0 < K; k0 += 64){
#pragma unroll
    for (int i = 0; i < 4; i++){
      int chunk = i * 4 + wv;
      async16(aptr[i] + k0, &As[chunk * 512 + l * 8]);
      async16(bptr[i] + k0, &Bs[chunk * 512 + l * 8]);
    }
    __syncthreads();
#pragma unroll
    for (int s = 0; s < 2; s++){
      const int so = (rr * 8 + ((quad + s * 4) ^ rr)) * 8;
      bf16x8 a[4], b[4];
#pragma unroll
      for (int i = 0; i < 4; i++) a[i] = *(const bf16x8*)&As[(wm * 8 + i * 2 + ch) * 512 + so];
#pragma unroll
      for (int j = 0; j < 4; j++) b[j] = *(const bf16x8*)&Bs[(wn * 8 + j * 2 + ch) * 512 + so];
#pragma unroll
      for (int i = 0; i < 4; i++)
#pragma unroll
        for (int j = 0; j < 4; j++)
          acc[i][j] = __builtin_amdgcn_mfma_f32_16x16x32_bf16(a[i], b[j], acc[i][j], 0, 0, 0);
    }
    __syncthreads();
  }

  if (MODE == MODE_WBF){
    u16* C = (u16*)Cv + (size_t)e * sCe;
    const float* wl = w_list + e * CAP;
#pragma unroll
    for (int i = 0; i < 4; i++)
#pragma unroll
      for (int r = 0; r < 4; r++){
        int row = m0 + wm * 64 + i * 16 + quad * 4 + r;
        if (row < n_valid){
          float wgt = wl[row];
#pragma unroll
          for (int j = 0; j < 4; j++){
            int cg = n0 + wn * 64 + j * 16 + col;
            C[(size_t)row * ldc + cg] = f2bf(wgt * acc[i][j][r]);
          }
        }
      }
  } else { // MODE_FINAL
    float* C = (float*)Cv;
#pragma unroll
    for (int i = 0; i < 4; i++)
#pragma unroll
      for (int r = 0; r < 4; r++){
        int row = m0 + wm * 64 + i * 16 + quad * 4 + r;
        int s0 = slot_map[row * 2 + 0];
        int s1 = slot_map[row * 2 + 1];
#pragma unroll
        for (int j = 0; j < 4; j++){
          int cg = n0 + wn * 64 + j * 16 + col;
          float v = acc[i][j][r];
          if (s0 >= 0) v += bf2f(Ebuf[(size_t)s0 * HD + cg]);
          if (s1 >= 0) v += bf2f(Ebuf[(size_t)s1 * HD + cg]);
          C[(size_t)row * HD + cg] = v;
        }
      }
  }
}

extern "C" void kernel_launch(void* const* d_in, const int* in_sizes, int n_in,
                              void* d_out, int out_size, void* d_ws, size_t ws_size,
                              hipStream_t stream){
  const float* x       = (const float*)d_in[0];
  const float* gate_w  = (const float*)d_in[1];
  const float* we_gate = (const float*)d_in[2];
  const float* we_up   = (const float*)d_in[3];
  const float* we_down = (const float*)d_in[4];
  const float* ws_gate = (const float*)d_in[5];
  const float* ws_up   = (const float*)d_in[6];
  const float* ws_down = (const float*)d_in[7];
  float* out = (float*)d_out;

  // ws layout. NOTE: Ebuf aliases [wg_bf .. wsu_bf] (20,971,520 elems each, exact):
  // those weights are dead after gu_kernel; Ebuf is written after (routed down) and
  // read by FINAL. Keeps peak ws at ~156 MB.
  char* p = (char*)d_ws;
  u16* x_bf   = (u16*)p; p += (size_t)NTOK * HD * 2;
  u16* wg_bf  = (u16*)p; p += (size_t)NEXP * 1024 * 1024 * 2;
  u16* wu_bf  = (u16*)p; p += (size_t)NEXP * 1024 * 1024 * 2;
  u16* wsg_bf = (u16*)p; p += (size_t)2048 * 1024 * 2;
  u16* wsu_bf = (u16*)p; p += (size_t)2048 * 1024 * 2;
  u16* wd_bf  = (u16*)p; p += (size_t)NEXP * 1024 * 1024 * 2;
  u16* wsd_bf = (u16*)p; p += (size_t)1024 * 2048 * 2;
  u16* Hr     = (u16*)p; p += (size_t)NEXP * CAP * 1024 * 2;  // routed H [8*2560, 1024]
  u16* Hs     = (u16*)p; p += (size_t)NTOK * 2048 * 2;        // shared H [8192, 2048]
  int*   topk_idx = (int*)p;   p += (size_t)NTOK * 2 * 4;
  float* topk_w   = (float*)p; p += (size_t)NTOK * 2 * 4;
  int*   tok_list = (int*)p;   p += (size_t)NEXP * CAP * 4;
  float* w_list   = (float*)p; p += (size_t)NEXP * CAP * 4;
  int*   slot_map = (int*)p;   p += (size_t)NTOK * 2 * 4;
  int*   ne       = (int*)p;   p += 128;
  u16* Ebuf = wg_bf;           // alias (see note above)

  // phase 1: all casts + router (40960 blocks: 2048 router + 38912 cast)
  prep_kernel<<<dim3(40960), dim3(256), 0, stream>>>(
      x, gate_w, we_gate, we_up, we_down, ws_gate, ws_up, ws_down,
      x_bf, wg_bf, wu_bf, wd_bf, wsg_bf, wsu_bf, wsd_bf, topk_idx, topk_w);

  // phase 2: capacity scan
  scan_kernel<<<dim3(1), dim3(256), 0, stream>>>(topk_idx, topk_w, tok_list, w_list, slot_map, ne);

  // phase 3: merged SwiGLU GEMMs (routed 2560 blocks + shared 2048 blocks)
  gu_kernel<<<dim3(4608), dim3(256), 0, stream>>>(
      x_bf, wg_bf, wu_bf, wsg_bf, wsu_bf, Hr, Hs, tok_list, ne);

  const long long WEXP = 1024LL * 1024;
  const long long SLOT = (long long)CAP * 1024;

  // phase 4: routed weighted down-proj -> Ebuf (aliases dead gate/up weights)
  gemm_bt<MODE_WBF><<<dim3(8, 20, 8), 256, 0, stream>>>(
      Hr, SLOT, wd_bf, WEXP, Ebuf, SLOT, 1024,
      w_list, ne, nullptr, nullptr, CAP, 1024);

  // phase 5: shared down-proj + routed combine -> out
  gemm_bt<MODE_FINAL><<<dim3(8, 64, 1), 256, 0, stream>>>(
      Hs, 0, wsd_bf, 0, out, 0, 1024,
      w_list, ne, Ebuf, slot_map, NTOK, 2048);
}

// Round 4
// 486.452 us; speedup vs baseline: 1.4555x; 1.1423x over previous
//
#include <hip/hip_runtime.h>

typedef unsigned short u16;

#define NTOK 8192
#define HD   1024
#define NEXP 8
#define CAP  2560   // ceil(1.25 * 8192 * 2 / 8) == 2560 == 20 * 128 tiles exactly

typedef __bf16 bf16x8 __attribute__((ext_vector_type(8)));
typedef float  f32x4  __attribute__((ext_vector_type(4)));

__device__ __forceinline__ u16 f2bf(float f){
  union { float f; unsigned u; } v; v.f = f;
  return (u16)((v.u + 0x7fffu + ((v.u >> 16) & 1u)) >> 16);   // RNE
}
__device__ __forceinline__ float bf2f(u16 h){
  union { unsigned u; float f; } v; v.u = ((unsigned)h) << 16; return v.f;
}

__device__ __forceinline__ void async16(const void* g, void* l){
  __builtin_amdgcn_global_load_lds((__attribute__((address_space(1))) void*)(g),
                                   (__attribute__((address_space(3))) void*)(l), 16, 0, 0);
}

// ---------------- prep: all 7 fp32->bf16 casts + router fused in one launch ----------------
__global__ __launch_bounds__(256)
void prep_kernel(const float* __restrict__ x, const float* __restrict__ gate_w,
                 const float* __restrict__ we_gate, const float* __restrict__ we_up,
                 const float* __restrict__ we_down, const float* __restrict__ ws_gate,
                 const float* __restrict__ ws_up, const float* __restrict__ ws_down,
                 u16* __restrict__ x_bf, u16* __restrict__ wg_bf, u16* __restrict__ wu_bf,
                 u16* __restrict__ wd_bf, u16* __restrict__ wsg_bf, u16* __restrict__ wsu_bf,
                 u16* __restrict__ wsd_bf,
                 int* __restrict__ topk_idx, float* __restrict__ topk_w){
  __shared__ float gw[NEXP * HD];
  int bid = blockIdx.x;
  int t = threadIdx.x;
  if (bid < 2048){
    // ---- router (4 tokens/block, fp64 logits, top-2, normalized weights) ----
    for (int i = t; i < NEXP * HD; i += 256) gw[i] = gate_w[i];
    __syncthreads();
    int wave = t >> 6, l = t & 63;
    int tok = bid * 4 + wave;
    const float* xr = x + (size_t)tok * HD;
    double acc[NEXP];
#pragma unroll
    for (int e = 0; e < NEXP; e++) acc[e] = 0.0;
    for (int j = 0; j < 16; j++){
      int h = j * 64 + l;
      double xv = (double)xr[h];
#pragma unroll
      for (int e = 0; e < NEXP; e++) acc[e] += xv * (double)gw[e * HD + h];
    }
#pragma unroll
    for (int e = 0; e < NEXP; e++){
      double v = acc[e];
#pragma unroll
      for (int off = 32; off > 0; off >>= 1) v += __shfl_down(v, off, 64);
      acc[e] = v;
    }
    if (l == 0){
      int i0 = 0; double l0 = acc[0];
#pragma unroll
      for (int e = 1; e < NEXP; e++) if (acc[e] > l0){ l0 = acc[e]; i0 = e; }
      int i1 = -1; double l1 = -1e300;
#pragma unroll
      for (int e = 0; e < NEXP; e++) if (e != i0 && acc[e] > l1){ l1 = acc[e]; i1 = e; }
      double e1 = exp(l1 - l0);
      double s  = 1.0 + e1;
      topk_idx[tok * 2 + 0] = i0;
      topk_idx[tok * 2 + 1] = i1;
      topk_w [tok * 2 + 0] = (float)(1.0 / s);
      topk_w [tok * 2 + 1] = (float)(e1 / s);
    }
  } else {
    // ---- cast (segments are multiples of 256 float4s; blocks never straddle) ----
    long long g = (long long)(bid - 2048) * 256 + t;   // float4 index
    const float4* s; ushort4* d; long long off;
    if      (g <  2097152){ s = (const float4*)x;       d = (ushort4*)x_bf;   off = 0; }
    else if (g <  4194304){ s = (const float4*)we_gate; d = (ushort4*)wg_bf;  off = 2097152; }
    else if (g <  6291456){ s = (const float4*)we_up;   d = (ushort4*)wu_bf;  off = 4194304; }
    else if (g <  8388608){ s = (const float4*)we_down; d = (ushort4*)wd_bf;  off = 6291456; }
    else if (g <  8912896){ s = (const float4*)ws_gate; d = (ushort4*)wsg_bf; off = 8388608; }
    else if (g <  9437184){ s = (const float4*)ws_up;   d = (ushort4*)wsu_bf; off = 8912896; }
    else                  { s = (const float4*)ws_down; d = (ushort4*)wsd_bf; off = 9437184; }
    long long i = g - off;
    float4 v = s[i];
    ushort4 o;
    o.x = f2bf(v.x); o.y = f2bf(v.y); o.z = f2bf(v.z); o.w = f2bf(v.w);
    d[i] = o;
  }
}

// ---------------- parallel capacity scan (stable), 2 passes of 64 blocks ----------------
// chunk = 256 consecutive slots per block. Rank within chunk via wave ballots; chunks
// prefixed via the global chunk_hist table. Order identical to a sequential cumsum.
__global__ __launch_bounds__(256)
void scan_p1(const int* __restrict__ topk_idx, int* __restrict__ chunk_hist){
  __shared__ int wcnt[4 * NEXP];
  int t = threadIdx.x, w = t >> 6, l = t & 63;
  int my_e = topk_idx[blockIdx.x * 256 + t];
#pragma unroll
  for (int e = 0; e < NEXP; e++){
    unsigned long long m = __ballot(my_e == e);
    if (l == e) wcnt[w * NEXP + e] = __popcll(m);
  }
  __syncthreads();
  if (t < NEXP){
    int s = 0;
#pragma unroll
    for (int w2 = 0; w2 < 4; w2++) s += wcnt[w2 * NEXP + t];
    chunk_hist[blockIdx.x * NEXP + t] = s;
  }
}

__global__ __launch_bounds__(256)
void scan_p2(const int* __restrict__ topk_idx, const float* __restrict__ topk_w,
             const int* __restrict__ chunk_hist,
             int* __restrict__ tok_list, float* __restrict__ w_list,
             int* __restrict__ slot_map, int* __restrict__ ne){
  __shared__ int hist_s[64 * NEXP];
  __shared__ int base_s[NEXP];
  __shared__ int wcnt[4 * NEXP];
  int t = threadIdx.x, w = t >> 6, l = t & 63;
  int chunk = blockIdx.x;
#pragma unroll
  for (int i = 0; i < 2; i++) hist_s[i * 256 + t] = chunk_hist[i * 256 + t];
  __syncthreads();
  if (t < NEXP){
    int b = 0, tot = 0;
    for (int c = 0; c < 64; c++){
      if (c == chunk) b = tot;
      tot += hist_s[c * NEXP + t];
    }
    base_s[t] = b;
    if (chunk == 0) ne[t] = tot < CAP ? tot : CAP;
  }
  int slot = chunk * 256 + t;
  int my_e = topk_idx[slot];
  float my_w = topk_w[slot];
  unsigned long long mymask = 0;
#pragma unroll
  for (int e = 0; e < NEXP; e++){
    unsigned long long m = __ballot(my_e == e);
    if (my_e == e) mymask = m;
    if (l == e) wcnt[w * NEXP + e] = __popcll(m);
  }
  __syncthreads();
  if (t < NEXP){
    int run = 0;
#pragma unroll
    for (int w2 = 0; w2 < 4; w2++){ int v = wcnt[w2 * NEXP + t]; wcnt[w2 * NEXP + t] = run; run += v; }
  }
  __syncthreads();
  int pos = base_s[my_e] + wcnt[w * NEXP + my_e] + __popcll(mymask & ((1ull << l) - 1ull));
  if (pos < CAP){
    tok_list[my_e * CAP + pos] = slot >> 1;
    w_list [my_e * CAP + pos] = my_w;
    slot_map[slot] = my_e * CAP + pos;
  } else {
    slot_map[slot] = -1;
  }
}

// ---------------- merged SwiGLU GEMM: routed (XCD-pinned experts) + shared ----------------
// blocks [0,2560): routed  e=bid&7 (expert pinned to XCD for L2 reuse), r=bid>>3:
//                  m0=(r>>4)*128, n0=(r&15)*64
// blocks [2560,4608): shared b2: n0=(b2/64)*64, m0=(b2%64)*128
__global__ __launch_bounds__(256)
void gu_kernel(const u16* __restrict__ x_bf,
               const u16* __restrict__ wg, const u16* __restrict__ wu,
               const u16* __restrict__ wsg, const u16* __restrict__ wsu,
               u16* __restrict__ Hr, u16* __restrict__ Hs,
               const int* __restrict__ tok_list, const int* __restrict__ ne)
{
  __shared__ u16 As[128 * 64];
  __shared__ u16 Bs[128 * 64];

  const int bid = blockIdx.x;
  const bool routed = bid < 2560;
  int m0, n0, ldc, n_valid;
  const u16 *B0, *B1;
  u16* C;
  const int* tl = nullptr;
  if (routed){
    int e = bid & 7, r = bid >> 3;
    m0 = (r >> 4) * 128; n0 = (r & 15) * 64;
    B0 = wg + (size_t)e * (1024 * 1024);
    B1 = wu + (size_t)e * (1024 * 1024);
    C  = Hr + (size_t)e * (CAP * 1024);
    ldc = 1024;
    n_valid = ne[e];
    tl = tok_list + e * CAP;
    if (m0 >= n_valid) return;
  } else {
    int b2 = bid - 2560;
    n0 = (b2 / 64) * 64; m0 = (b2 % 64) * 128;
    B0 = wsg; B1 = wsu; C = Hs; ldc = 2048; n_valid = 1 << 30;
  }

  const int tid = threadIdx.x;
  const int wv  = tid >> 6;
  const int l   = tid & 63;
  const int lr  = l >> 3;             // row within 8-row chunk
  const int cb  = (l & 7) ^ lr;       // XOR-swizzled col-block (16B units)

  const u16* aptr[4];
  const u16* bptr[4];
#pragma unroll
  for (int i = 0; i < 4; i++){
    int chunk = i * 4 + wv;
    int arow  = m0 + chunk * 8 + lr;
    if (routed){
      int r2 = arow < n_valid ? arow : (n_valid - 1);
      aptr[i] = x_bf + (size_t)tl[r2] * 1024 + cb * 8;
    } else {
      aptr[i] = x_bf + (size_t)arow * 1024 + cb * 8;
    }
    int rn = chunk * 8 + lr;          // B tile row 0..127
    int w  = rn >> 6;                 // which wave-half of N
    int jq = (rn >> 4) & 3;           // 0,1 = gate ; 2,3 = up (uniform per chunk)
    int rl = rn & 15;
    int icol = n0 + w * 32 + (jq & 1) * 16 + rl;
    bptr[i] = ((jq < 2) ? B0 : B1) + (size_t)icol * 1024 + cb * 8;
  }

  const int wm = wv & 1, wn = wv >> 1;
  const int col = l & 15, quad = l >> 4;
  const int rr = col & 7, ch = col >> 3;

  f32x4 acc[4][4];
#pragma unroll
  for (int i = 0; i < 4; i++)
#pragma unroll
    for (int j = 0; j < 4; j++)
      acc[i][j] = (f32x4){0.f, 0.f, 0.f, 0.f};

  for (int k0 = 0; k0 < 1024; k0 += 64){
#pragma unroll
    for (int i = 0; i < 4; i++){
      int chunk = i * 4 + wv;
      async16(aptr[i] + k0, &As[chunk * 512 + l * 8]);
      async16(bptr[i] + k0, &Bs[chunk * 512 + l * 8]);
    }
    __syncthreads();
#pragma unroll
    for (int s = 0; s < 2; s++){
      const int so = (rr * 8 + ((quad + s * 4) ^ rr)) * 8;   // swizzled fragment offset
      bf16x8 a[4], b[4];
#pragma unroll
      for (int i = 0; i < 4; i++) a[i] = *(const bf16x8*)&As[(wm * 8 + i * 2 + ch) * 512 + so];
#pragma unroll
      for (int j = 0; j < 4; j++) b[j] = *(const bf16x8*)&Bs[(wn * 8 + j * 2 + ch) * 512 + so];
#pragma unroll
      for (int i = 0; i < 4; i++)
#pragma unroll
        for (int j = 0; j < 4; j++)
          acc[i][j] = __builtin_amdgcn_mfma_f32_16x16x32_bf16(a[i], b[j], acc[i][j], 0, 0, 0);
    }
    __syncthreads();
  }

  // epilogue: silu(g)*u -> bf16
#pragma unroll
  for (int i = 0; i < 4; i++)
#pragma unroll
    for (int r = 0; r < 4; r++){
      int row = m0 + wm * 64 + i * 16 + quad * 4 + r;
#pragma unroll
      for (int j = 0; j < 2; j++){
        int cg = n0 + wn * 32 + j * 16 + col;
        float g = acc[i][j][r], u = acc[i][j + 2][r];
        float h = (g / (1.f + __expf(-g))) * u;
        C[(size_t)row * ldc + cg] = f2bf(h);
      }
    }
}

// ---------------- merged down-proj: routed WBF (-> Ebuf) + shared (-> out), one launch ----------------
// blocks [0,1280): routed e=bid&7 (XCD-pinned), r=bid>>3: m0=(r/8)*128, n0=(r%8)*128, K=1024
//                  C = Ebuf[slot] = w_list[slot] * (Hr @ wd^T), bf16
// blocks [1280,1792): shared b2: n0=(b2&7)*128, m0=(b2>>3)*128, K=2048
//                  out = Hs @ wsd^T, fp32 (plain store; combine adds routed after)
__global__ __launch_bounds__(256)
void down_kernel(const u16* __restrict__ Hr, const u16* __restrict__ wd,
                 const u16* __restrict__ Hs, const u16* __restrict__ wsd,
                 u16* __restrict__ Ebuf, float* __restrict__ out,
                 const float* __restrict__ w_list, const int* __restrict__ ne)
{
  __shared__ u16 As[128 * 64];
  __shared__ u16 Bs[128 * 64];

  const int bid = blockIdx.x;
  const bool routed = bid < 1280;
  int m0, n0, n_valid, K, e = 0;
  const u16 *Ab, *Bb;
  if (routed){
    e = bid & 7; int r = bid >> 3;
    m0 = (r >> 3) * 128; n0 = (r & 7) * 128;
    Ab = Hr + (size_t)e * (CAP * 1024);
    Bb = wd + (size_t)e * (1024 * 1024);
    K = 1024;
    n_valid = ne[e];
    if (m0 >= n_valid) return;
  } else {
    int b2 = bid - 1280;
    n0 = (b2 & 7) * 128; m0 = (b2 >> 3) * 128;
    Ab = Hs; Bb = wsd; K = 2048; n_valid = 1 << 30;
  }

  const int tid = threadIdx.x;
  const int wv  = tid >> 6;
  const int l   = tid & 63;
  const int lr  = l >> 3;
  const int cb  = (l & 7) ^ lr;

  const u16* aptr[4];
  const u16* bptr[4];
#pragma unroll
  for (int i = 0; i < 4; i++){
    int chunk = i * 4 + wv;
    aptr[i] = Ab + (size_t)(m0 + chunk * 8 + lr) * K + cb * 8;
    bptr[i] = Bb + (size_t)(n0 + chunk * 8 + lr) * K + cb * 8;
  }

  const int wm = wv & 1, wn = wv >> 1;
  const int col = l & 15, quad = l >> 4;
  const int rr = col & 7, ch = col >> 3;

  f32x4 acc[4][4];
#pragma unroll
  for (int i = 0; i < 4; i++)
#pragma unroll
    for (int j = 0; j < 4; j++)
      acc[i][j] = (f32x4){0.f, 0.f, 0.f, 0.f};

  for (int k0 = 0; k0 < K; k0 += 64){
#pragma unroll
    for (int i = 0; i < 4; i++){
      int chunk = i * 4 + wv;
      async16(aptr[i] + k0, &As[chunk * 512 + l * 8]);
      async16(bptr[i] + k0, &Bs[chunk * 512 + l * 8]);
    }
    __syncthreads();
#pragma unroll
    for (int s = 0; s < 2; s++){
      const int so = (rr * 8 + ((quad + s * 4) ^ rr)) * 8;
      bf16x8 a[4], b[4];
#pragma unroll
      for (int i = 0; i < 4; i++) a[i] = *(const bf16x8*)&As[(wm * 8 + i * 2 + ch) * 512 + so];
#pragma unroll
      for (int j = 0; j < 4; j++) b[j] = *(const bf16x8*)&Bs[(wn * 8 + j * 2 + ch) * 512 + so];
#pragma unroll
      for (int i = 0; i < 4; i++)
#pragma unroll
        for (int j = 0; j < 4; j++)
          acc[i][j] = __builtin_amdgcn_mfma_f32_16x16x32_bf16(a[i], b[j], acc[i][j], 0, 0, 0);
    }
    __syncthreads();
  }

  if (routed){
    u16* C = Ebuf + (size_t)e * (CAP * 1024);
    const float* wl = w_list + e * CAP;
#pragma unroll
    for (int i = 0; i < 4; i++)
#pragma unroll
      for (int r = 0; r < 4; r++){
        int row = m0 + wm * 64 + i * 16 + quad * 4 + r;
        if (row < n_valid){
          float wgt = wl[row];
#pragma unroll
          for (int j = 0; j < 4; j++){
            int cg = n0 + wn * 64 + j * 16 + col;
            C[(size_t)row * 1024 + cg] = f2bf(wgt * acc[i][j][r]);
          }
        }
      }
  } else {
#pragma unroll
    for (int i = 0; i < 4; i++)
#pragma unroll
      for (int r = 0; r < 4; r++){
        int row = m0 + wm * 64 + i * 16 + quad * 4 + r;
#pragma unroll
        for (int j = 0; j < 4; j++){
          int cg = n0 + wn * 64 + j * 16 + col;
          out[(size_t)row * 1024 + cg] = acc[i][j][r];
        }
      }
  }
}

// ---------------- combine: out[tok] += Ebuf[slot0] + Ebuf[slot1] ----------------
__global__ __launch_bounds__(256)
void combine_kernel(float* __restrict__ out, const u16* __restrict__ Ebuf,
                    const int* __restrict__ slot_map){
  long long g = (long long)blockIdx.x * 256 + threadIdx.x;  // float4 index into out
  int row = (int)(g >> 8);          // 256 float4 per 1024-col row
  int c4  = (int)(g & 255);
  int s0 = slot_map[row * 2 + 0];
  int s1 = slot_map[row * 2 + 1];
  float4 v = ((float4*)out)[g];
  if (s0 >= 0){
    ushort4 a = ((const ushort4*)Ebuf)[(size_t)s0 * 256 + c4];
    v.x += bf2f(a.x); v.y += bf2f(a.y); v.z += bf2f(a.z); v.w += bf2f(a.w);
  }
  if (s1 >= 0){
    ushort4 a = ((const ushort4*)Ebuf)[(size_t)s1 * 256 + c4];
    v.x += bf2f(a.x); v.y += bf2f(a.y); v.z += bf2f(a.z); v.w += bf2f(a.w);
  }
  ((float4*)out)[g] = v;
}

extern "C" void kernel_launch(void* const* d_in, const int* in_sizes, int n_in,
                              void* d_out, int out_size, void* d_ws, size_t ws_size,
                              hipStream_t stream){
  const float* x       = (const float*)d_in[0];
  const float* gate_w  = (const float*)d_in[1];
  const float* we_gate = (const float*)d_in[2];
  const float* we_up   = (const float*)d_in[3];
  const float* we_down = (const float*)d_in[4];
  const float* ws_gate = (const float*)d_in[5];
  const float* ws_up   = (const float*)d_in[6];
  const float* ws_down = (const float*)d_in[7];
  float* out = (float*)d_out;

  // ws layout. Ebuf aliases [wg_bf .. wsu_bf] (41,943,040 B each, exact): gate/up
  // weights are dead after gu_kernel; Ebuf is written by down_kernel afterwards.
  char* p = (char*)d_ws;
  u16* x_bf   = (u16*)p; p += (size_t)NTOK * HD * 2;
  u16* wg_bf  = (u16*)p; p += (size_t)NEXP * 1024 * 1024 * 2;
  u16* wu_bf  = (u16*)p; p += (size_t)NEXP * 1024 * 1024 * 2;
  u16* wsg_bf = (u16*)p; p += (size_t)2048 * 1024 * 2;
  u16* wsu_bf = (u16*)p; p += (size_t)2048 * 1024 * 2;
  u16* wd_bf  = (u16*)p; p += (size_t)NEXP * 1024 * 1024 * 2;
  u16* wsd_bf = (u16*)p; p += (size_t)1024 * 2048 * 2;
  u16* Hr     = (u16*)p; p += (size_t)NEXP * CAP * 1024 * 2;  // routed H [8*2560, 1024]
  u16* Hs     = (u16*)p; p += (size_t)NTOK * 2048 * 2;        // shared H [8192, 2048]
  int*   topk_idx   = (int*)p;   p += (size_t)NTOK * 2 * 4;
  float* topk_w     = (float*)p; p += (size_t)NTOK * 2 * 4;
  int*   tok_list   = (int*)p;   p += (size_t)NEXP * CAP * 4;
  float* w_list     = (float*)p; p += (size_t)NEXP * CAP * 4;
  int*   slot_map   = (int*)p;   p += (size_t)NTOK * 2 * 4;
  int*   chunk_hist = (int*)p;   p += 64 * NEXP * 4;
  int*   ne         = (int*)p;   p += 128;
  u16* Ebuf = wg_bf;             // alias (see note above)

  // phase 1: all casts + router
  prep_kernel<<<dim3(40960), dim3(256), 0, stream>>>(
      x, gate_w, we_gate, we_up, we_down, ws_gate, ws_up, ws_down,
      x_bf, wg_bf, wu_bf, wd_bf, wsg_bf, wsu_bf, wsd_bf, topk_idx, topk_w);

  // phase 2: parallel capacity scan (stable)
  scan_p1<<<dim3(64), dim3(256), 0, stream>>>(topk_idx, chunk_hist);
  scan_p2<<<dim3(64), dim3(256), 0, stream>>>(topk_idx, topk_w, chunk_hist,
                                              tok_list, w_list, slot_map, ne);

  // phase 3: merged SwiGLU GEMMs (routed 2560 + shared 2048 blocks)
  gu_kernel<<<dim3(4608), dim3(256), 0, stream>>>(
      x_bf, wg_bf, wu_bf, wsg_bf, wsu_bf, Hr, Hs, tok_list, ne);

  // phase 4: merged down-proj (routed 1280 -> Ebuf, shared 512 -> out)
  down_kernel<<<dim3(1792), dim3(256), 0, stream>>>(
      Hr, wd_bf, Hs, wsd_bf, Ebuf, out, w_list, ne);

  // phase 5: combine routed contributions into out
  combine_kernel<<<dim3(8192), dim3(256), 0, stream>>>(out, Ebuf, slot_map);
}